// Round 4
// baseline (1008.553 us; speedup 1.0000x reference)
//
#include <hip/hip_runtime.h>
#include <hip/hip_bf16.h>

#define BB 8
#define CC 16
#define HH 128
#define WW 128
#define HD 64
#define WD 64
#define LP 4096
#define K1 144
#define KP 160
#define N2 256

typedef __attribute__((ext_vector_type(8))) short bf16x8;
typedef __attribute__((ext_vector_type(4))) float f32x4;

__device__ __forceinline__ unsigned short pack_rne(float x) {
    unsigned int u = __float_as_uint(x);
    return (unsigned short)((u + 0x7FFFu + ((u >> 16) & 1u)) >> 16);
}
__device__ __forceinline__ float bf2f(unsigned short u) {
    return __uint_as_float(((unsigned int)u) << 16);
}
__device__ __forceinline__ float ld_in(const void* p, long idx, int bf) {
    if (bf) return bf2f(((const unsigned short*)p)[idx]);
    return ((const float*)p)[idx];
}

// ---------------------------------------------------------------------------
__global__ void detect_kernel(const unsigned int* __restrict__ w, int* __restrict__ flag) {
    if (threadIdx.x == 0) {
        int cnt = 0;
        for (int i = 0; i < 256; i++) {
            unsigned int e = (w[i] >> 7) & 0xFF;
            if (e >= 100 && e <= 140) cnt++;
        }
        *flag = (cnt >= 192) ? 1 : 0;
    }
}

// ---------------------------------------------------------------------------
// prep v2: one wave per patch; shuffle-butterfly reductions, no LDS/barriers.
// ---------------------------------------------------------------------------
__global__ __launch_bounds__(256) void prep_kernel(
    const void* __restrict__ fg, const void* __restrict__ bg,
    const void* __restrict__ mask, const int* __restrict__ flagp,
    unsigned short* __restrict__ Fh, unsigned short* __restrict__ Fl,
    unsigned short* __restrict__ Kh, unsigned short* __restrict__ Kl,
    float* __restrict__ mmg)
{
    int bf = *flagp;
    int wave = threadIdx.x >> 6, lane = threadIdx.x & 63;
    int bl = blockIdx.x * 4 + wave;
    int b = bl >> 12, l = bl & 4095;
    int py = l >> 6, px = l & 63;

    float fgv[3], bgv[3];
    float ss = 0.f;
#pragma unroll
    for (int j = 0; j < 3; j++) {
        int e = lane + 64 * j;
        fgv[j] = 0.f; bgv[j] = 0.f;
        if (e < K1) {
            int c = e / 9;
            int r9 = e - c * 9;
            int ky = r9 / 3, kx = r9 - ky * 3;
            int yy = py + ky - 1, xx = px + kx - 1;
            if (yy >= 0 && yy < HD && xx >= 0 && xx < WD) {
                long base = ((long)(b * CC + c) * HH + 2 * yy) * WW + 2 * xx;
                fgv[j] = ld_in(fg, base, bf);
                bgv[j] = ld_in(bg, base, bf);
            }
        }
        ss += bgv[j] * bgv[j];
    }
#pragma unroll
    for (int s = 1; s < 64; s <<= 1) ss += __shfl_xor(ss, s);
    float rn = 1.0f / fmaxf(sqrtf(ss), 1e-4f);

    float mv = 0.f;
    if (lane < 9) {
        int ky = lane / 3, kx = lane - ky * 3;
        int yy = py + ky - 1, xx = px + kx - 1;
        if (yy >= 0 && yy < HD && xx >= 0 && xx < WD)
            mv = ld_in(mask, ((long)b * HH + 2 * yy) * WW + 2 * xx, bf);
    }
#pragma unroll
    for (int s = 1; s < 16; s <<= 1) mv += __shfl_xor(mv, s);
    if (lane == 0) mmg[bl] = (mv == 0.0f) ? 1.0f : 0.0f;

    long base = (long)bl * KP;
#pragma unroll
    for (int j = 0; j < 3; j++) {
        int e = lane + 64 * j;
        if (e < KP) {
            float f = fgv[j];
            float kv = bgv[j] * rn;
            unsigned short fh = pack_rne(f);
            unsigned short fl = pack_rne(f - bf2f(fh));
            unsigned short kh = pack_rne(kv);
            unsigned short kl = pack_rne(kv - bf2f(kh));
            Fh[base + e] = fh; Fl[base + e] = fl;
            Kh[base + e] = kh; Kl[base + e] = kl;
        }
    }
}

// ---------------------------------------------------------------------------
__global__ __launch_bounds__(256) void vT_kernel(
    const void* __restrict__ bg, const int* __restrict__ flagp,
    unsigned short* __restrict__ VT)
{
    int bf = *flagp;
    int l0 = blockIdx.x * 16;
    int b = blockIdx.y;
    int j = threadIdx.x;
    int c = j >> 4, dy = (j >> 2) & 3, dx = j & 3;

    unsigned short buf[16];
#pragma unroll
    for (int i = 0; i < 16; i++) {
        int l = l0 + i;
        int ly = l >> 6, lx = l & 63;
        int Y = 2 * ly + dy - 1, X = 2 * lx + dx - 1;
        float v = 0.f;
        if (Y >= 0 && Y < HH && X >= 0 && X < WW)
            v = ld_in(bg, ((long)(b * CC + c) * HH + Y) * WW + X, bf);
        buf[i] = pack_rne(v);
    }
    uint4* dst = (uint4*)&VT[((size_t)(b * N2 + j)) * LP + l0];
    dst[0] = *(uint4*)&buf[0];
    dst[1] = *(uint4*)&buf[8];
}

// ---------------------------------------------------------------------------
// flash: fused gemmZ + softmax + gemmU. One wave owns 16 p-rows; F frags in
// registers; l swept in chunks of 32. S via 3-pass split-bf16 MFMA (mapping
// identical to verified gemmZ); online softmax with deferred max (THR=10);
// P transposed D-frag -> A-frag through a per-wave 16x40 LDS tile (read
// pattern identical to verified gemmU Ws); O-MFMA with direct-global V
// B-frags (identical to verified gemmU Vs mapping). No barriers; waves
// fully independent. Grid (64 p-tiles, 8 batches) = 512 blocks = 2/CU.
// XCD swizzle: fid%8 = batch, so each XCD keeps one batch's K+VT in L2.
// ---------------------------------------------------------------------------
__global__ __launch_bounds__(256, 2) void flash_kernel(
    const unsigned short* __restrict__ Fh, const unsigned short* __restrict__ Fl,
    const unsigned short* __restrict__ Kh, const unsigned short* __restrict__ Kl,
    const unsigned short* __restrict__ VT,  // [BB][256][4096]
    const float* __restrict__ mmg,          // [BB][4096]
    float* __restrict__ U)                  // [BB][4096][256]
{
    __shared__ unsigned short P_lds[4][16][40];

    int t = threadIdx.x;
    int wave = t >> 6, lane = t & 63;
    int l15 = lane & 15, lq = lane >> 4;

    int fid = blockIdx.y * 64 + blockIdx.x;
    int b = fid & 7;                 // XCD-locality: fid%8 -> same XCD, same batch
    int p0 = (fid >> 3) * 64;
    int pw = p0 + wave * 16;

    const unsigned short* Fh_b = Fh + (size_t)b * LP * KP;
    const unsigned short* Fl_b = Fl + (size_t)b * LP * KP;
    const unsigned short* Kh_b = Kh + (size_t)b * LP * KP;
    const unsigned short* Kl_b = Kl + (size_t)b * LP * KP;
    const unsigned short* VT_b = VT + (size_t)b * N2 * LP;
    const float* mm_b = mmg + (size_t)b * LP;

    // F fragments for this wave's 16 rows: row = pw + l15, k = kc*32 + lq*8
    bf16x8 fh[5], fl[5];
    {
        size_t fbase = (size_t)(pw + l15) * KP + lq * 8;
#pragma unroll
        for (int kc = 0; kc < 5; kc++) {
            fh[kc] = *(const bf16x8*)&Fh_b[fbase + kc * 32];
            fl[kc] = *(const bf16x8*)&Fl_b[fbase + kc * 32];
        }
    }

    f32x4 zero4 = {0.f, 0.f, 0.f, 0.f};
    f32x4 acc[16];
#pragma unroll
    for (int n = 0; n < 16; n++) acc[n] = zero4;

    float m_[4] = {0.f, 0.f, 0.f, 0.f};   // running max for rows p = lq*4+r
    float d_[4] = {0.f, 0.f, 0.f, 0.f};   // running denom (partial per lane)

    for (int ch = 0; ch < 128; ch++) {
        int l0 = ch * 32;

        // ---- S phase: two 16-wide l-subtiles
        float z[2][4];
        float mmh[2];
#pragma unroll
        for (int h = 0; h < 2; h++) {
            int lb = l0 + h * 16;
            size_t kbase = (size_t)(lb + l15) * KP + lq * 8;
            bf16x8 kh[5], kl[5];
#pragma unroll
            for (int kc = 0; kc < 5; kc++) {
                kh[kc] = *(const bf16x8*)&Kh_b[kbase + kc * 32];
                kl[kc] = *(const bf16x8*)&Kl_b[kbase + kc * 32];
            }
            mmh[h] = mm_b[lb + l15];
            f32x4 s = zero4;
#pragma unroll
            for (int kc = 0; kc < 5; kc++) {
                s = __builtin_amdgcn_mfma_f32_16x16x32_bf16(fh[kc], kh[kc], s, 0, 0, 0);
                s = __builtin_amdgcn_mfma_f32_16x16x32_bf16(fh[kc], kl[kc], s, 0, 0, 0);
                s = __builtin_amdgcn_mfma_f32_16x16x32_bf16(fl[kc], kh[kc], s, 0, 0, 0);
            }
#pragma unroll
            for (int r = 0; r < 4; r++)
                z[h][r] = (mmh[h] > 0.f) ? 10.f * s[r] : 0.f;
        }

        // ---- online softmax. Row p = lq*4+r spans the 16 lanes of this lq
        // group (col = l15); reduce max across them (xor 1,2,4,8 stays in-group).
        float pm[4];
#pragma unroll
        for (int r = 0; r < 4; r++) pm[r] = fmaxf(z[0][r], z[1][r]);
#pragma unroll
        for (int s = 1; s < 16; s <<= 1) {
#pragma unroll
            for (int r = 0; r < 4; r++) pm[r] = fmaxf(pm[r], __shfl_xor(pm[r], s));
        }
        // deferred rescale (THR=10): branch uniform within each 16-lane group
#pragma unroll
        for (int r = 0; r < 4; r++) {
            if (pm[r] > m_[r] + 10.f) {
                float sc = __expf(m_[r] - pm[r]);
                d_[r] *= sc;
#pragma unroll
                for (int n = 0; n < 16; n++) acc[n][r] *= sc;
                m_[r] = pm[r];
            }
        }

        // e, denom, P write (D-frag -> [p][l] layout in per-wave LDS tile)
#pragma unroll
        for (int h = 0; h < 2; h++) {
#pragma unroll
            for (int r = 0; r < 4; r++) {
                float e = __expf(z[h][r] - m_[r]);
                d_[r] += e;
                P_lds[wave][lq * 4 + r][h * 16 + l15] = pack_rne(e * mmh[h]);
            }
        }
        asm volatile("" ::: "memory");
        // A-frag read: row = l15, k = lq*8 (same pattern as verified gemmU Ws)
        bf16x8 pa = *(const bf16x8*)&P_lds[wave][l15][lq * 8];

        // ---- O phase: 16 c-tiles in two groups of 8 (register pressure)
#pragma unroll
        for (int g = 0; g < 2; g++) {
            bf16x8 vb[8];
            size_t vbase = (size_t)(g * 128 + l15) * LP + l0 + lq * 8;
#pragma unroll
            for (int n = 0; n < 8; n++)
                vb[n] = *(const bf16x8*)&VT_b[vbase + (size_t)(n * 16) * LP];
#pragma unroll
            for (int n = 0; n < 8; n++)
                acc[g * 8 + n] = __builtin_amdgcn_mfma_f32_16x16x32_bf16(pa, vb[n], acc[g * 8 + n], 0, 0, 0);
        }
    }

    // ---- epilogue: finish denom across the 16 lanes of each row, normalize
#pragma unroll
    for (int s = 1; s < 16; s <<= 1) {
#pragma unroll
        for (int r = 0; r < 4; r++) d_[r] += __shfl_xor(d_[r], s);
    }
    float dinv[4];
#pragma unroll
    for (int r = 0; r < 4; r++) dinv[r] = 1.0f / d_[r];

    float* U_b = U + (size_t)b * LP * N2;
#pragma unroll
    for (int n = 0; n < 16; n++) {
        int col = (n >> 3) * 128 + (n & 7) * 16 + l15;
#pragma unroll
        for (int r = 0; r < 4; r++)
            U_b[(size_t)(pw + lq * 4 + r) * N2 + col] = acc[n][r] * dinv[r];
    }
}

// ---------------------------------------------------------------------------
// gather / overlap-add (upright), fp32 out
// ---------------------------------------------------------------------------
__global__ __launch_bounds__(256) void gather_kernel(
    const float* __restrict__ U, float* __restrict__ out)
{
    int idx = blockIdx.x * 256 + threadIdx.x;
    int ox = idx & 127;
    int t1 = idx >> 7;
    int oy = t1 & 127;
    int t2 = t1 >> 7;
    int c = t2 & 15;
    int b = t2 >> 4;

    float sum = 0.f;
    int d0y = (oy + 1) & 1, d0x = (ox + 1) & 1;
#pragma unroll
    for (int iy = 0; iy < 2; iy++) {
        int dy = d0y + 2 * iy;
        int y = (oy + 1 - dy) >> 1;
        if (y < 0 || y > 63) continue;
#pragma unroll
        for (int ix = 0; ix < 2; ix++) {
            int dx = d0x + 2 * ix;
            int x = (ox + 1 - dx) >> 1;
            if (x < 0 || x > 63) continue;
            sum += U[((long)b * LP + y * 64 + x) * N2 + c * 16 + dy * 4 + dx];
        }
    }
    out[idx] = sum * 0.25f;
}

// ---------------------------------------------------------------------------
extern "C" void kernel_launch(void* const* d_in, const int* in_sizes, int n_in,
                              void* d_out, int out_size, void* d_ws, size_t ws_size,
                              hipStream_t stream)
{
    const void* fg   = d_in[0];
    const void* bg   = d_in[1];
    const void* mask = d_in[2];
    float* out = (float*)d_out;

    char* w = (char*)d_ws;
    size_t o = 0;
    int*            flag = (int*)(w + o);            o += 16;
    unsigned short* Fh   = (unsigned short*)(w + o); o += (size_t)BB * LP * KP * 2;
    unsigned short* Fl   = (unsigned short*)(w + o); o += (size_t)BB * LP * KP * 2;
    unsigned short* Kh   = (unsigned short*)(w + o); o += (size_t)BB * LP * KP * 2;
    unsigned short* Kl   = (unsigned short*)(w + o); o += (size_t)BB * LP * KP * 2;
    unsigned short* VT   = (unsigned short*)(w + o); o += (size_t)BB * N2 * LP * 2;
    float*          U    = (float*)(w + o);          o += (size_t)BB * LP * N2 * 4;
    float*          mmg  = (float*)(w + o);          o += (size_t)BB * LP * 4;

    detect_kernel<<<1, 64, 0, stream>>>((const unsigned int*)fg, flag);
    prep_kernel<<<BB * LP / 4, 256, 0, stream>>>(fg, bg, mask, flag, Fh, Fl, Kh, Kl, mmg);
    vT_kernel<<<dim3(LP / 16, BB), 256, 0, stream>>>(bg, flag, VT);

    flash_kernel<<<dim3(64, 8), 256, 0, stream>>>(Fh, Fl, Kh, Kl, VT, mmg, U);

    gather_kernel<<<(BB * CC * HH * WW) / 256, 256, 0, stream>>>(U, out);
}

// Round 5
// 781.985 us; speedup vs baseline: 1.2897x; 1.2897x over previous
//
#include <hip/hip_runtime.h>
#include <hip/hip_bf16.h>

#define BB 8
#define CC 16
#define HH 128
#define WW 128
#define HD 64
#define WD 64
#define LP 4096
#define K1 144
#define KP 160
#define N2 256
#define NS 4
#define NCH 32   // (LP/NS)/32 chunks per block

typedef __attribute__((ext_vector_type(8))) short bf16x8;
typedef __attribute__((ext_vector_type(4))) float f32x4;

__device__ __forceinline__ unsigned short pack_rne(float x) {
    unsigned int u = __float_as_uint(x);
    return (unsigned short)((u + 0x7FFFu + ((u >> 16) & 1u)) >> 16);
}
__device__ __forceinline__ float bf2f(unsigned short u) {
    return __uint_as_float(((unsigned int)u) << 16);
}
__device__ __forceinline__ float ld_in(const void* p, long idx, int bf) {
    if (bf) return bf2f(((const unsigned short*)p)[idx]);
    return ((const float*)p)[idx];
}
__device__ __forceinline__ void gl_lds16(const void* g, void* l) {
    __builtin_amdgcn_global_load_lds(
        (const __attribute__((address_space(1))) unsigned int*)g,
        (__attribute__((address_space(3))) unsigned int*)l,
        16, 0, 0);
}

// ---------------------------------------------------------------------------
__global__ void detect_kernel(const unsigned int* __restrict__ w, int* __restrict__ flag) {
    if (threadIdx.x == 0) {
        int cnt = 0;
        for (int i = 0; i < 256; i++) {
            unsigned int e = (w[i] >> 7) & 0xFF;
            if (e >= 100 && e <= 140) cnt++;
        }
        *flag = (cnt >= 192) ? 1 : 0;
    }
}

// ---------------------------------------------------------------------------
// prep v2: one wave per patch; shuffle-butterfly reductions, no LDS/barriers.
// ---------------------------------------------------------------------------
__global__ __launch_bounds__(256) void prep_kernel(
    const void* __restrict__ fg, const void* __restrict__ bg,
    const void* __restrict__ mask, const int* __restrict__ flagp,
    unsigned short* __restrict__ Fh, unsigned short* __restrict__ Fl,
    unsigned short* __restrict__ Kh, unsigned short* __restrict__ Kl,
    float* __restrict__ mmg)
{
    int bf = *flagp;
    int wave = threadIdx.x >> 6, lane = threadIdx.x & 63;
    int bl = blockIdx.x * 4 + wave;
    int b = bl >> 12, l = bl & 4095;
    int py = l >> 6, px = l & 63;

    float fgv[3], bgv[3];
    float ss = 0.f;
#pragma unroll
    for (int j = 0; j < 3; j++) {
        int e = lane + 64 * j;
        fgv[j] = 0.f; bgv[j] = 0.f;
        if (e < K1) {
            int c = e / 9;
            int r9 = e - c * 9;
            int ky = r9 / 3, kx = r9 - ky * 3;
            int yy = py + ky - 1, xx = px + kx - 1;
            if (yy >= 0 && yy < HD && xx >= 0 && xx < WD) {
                long base = ((long)(b * CC + c) * HH + 2 * yy) * WW + 2 * xx;
                fgv[j] = ld_in(fg, base, bf);
                bgv[j] = ld_in(bg, base, bf);
            }
        }
        ss += bgv[j] * bgv[j];
    }
#pragma unroll
    for (int s = 1; s < 64; s <<= 1) ss += __shfl_xor(ss, s);
    float rn = 1.0f / fmaxf(sqrtf(ss), 1e-4f);

    float mv = 0.f;
    if (lane < 9) {
        int ky = lane / 3, kx = lane - ky * 3;
        int yy = py + ky - 1, xx = px + kx - 1;
        if (yy >= 0 && yy < HD && xx >= 0 && xx < WD)
            mv = ld_in(mask, ((long)b * HH + 2 * yy) * WW + 2 * xx, bf);
    }
#pragma unroll
    for (int s = 1; s < 16; s <<= 1) mv += __shfl_xor(mv, s);
    if (lane == 0) mmg[bl] = (mv == 0.0f) ? 1.0f : 0.0f;

    long base = (long)bl * KP;
#pragma unroll
    for (int j = 0; j < 3; j++) {
        int e = lane + 64 * j;
        if (e < KP) {
            float f = fgv[j];
            float kv = bgv[j] * rn;
            unsigned short fh = pack_rne(f);
            unsigned short fl = pack_rne(f - bf2f(fh));
            unsigned short kh = pack_rne(kv);
            unsigned short kl = pack_rne(kv - bf2f(kh));
            Fh[base + e] = fh; Fl[base + e] = fl;
            Kh[base + e] = kh; Kl[base + e] = kl;
        }
    }
}

// ---------------------------------------------------------------------------
__global__ __launch_bounds__(256) void vT_kernel(
    const void* __restrict__ bg, const int* __restrict__ flagp,
    unsigned short* __restrict__ VT)
{
    int bf = *flagp;
    int l0 = blockIdx.x * 16;
    int b = blockIdx.y;
    int j = threadIdx.x;
    int c = j >> 4, dy = (j >> 2) & 3, dx = j & 3;

    unsigned short buf[16];
#pragma unroll
    for (int i = 0; i < 16; i++) {
        int l = l0 + i;
        int ly = l >> 6, lx = l & 63;
        int Y = 2 * ly + dy - 1, X = 2 * lx + dx - 1;
        float v = 0.f;
        if (Y >= 0 && Y < HH && X >= 0 && X < WW)
            v = ld_in(bg, ((long)(b * CC + c) * HH + Y) * WW + X, bf);
        buf[i] = pack_rne(v);
    }
    uint4* dst = (uint4*)&VT[((size_t)(b * N2 + j)) * LP + l0];
    dst[0] = *(uint4*)&buf[0];
    dst[1] = *(uint4*)&buf[8];
}

// ---------------------------------------------------------------------------
// flash v3: fused S/softmax/O with
//  - split-l (NS=4): each block covers 1024 l; partial acc + partial denom
//    stored to slabs, combined by merge_kernel. Softmax uses FIXED shift 60
//    (shift-invariant; masked cols pin row-max >= 0, data bounds z <~ 70,
//    so e^(z-60) stays in fp range) -> partials are simply additive.
//  - K tiles (Kh+Kl, 32 l-rows) staged to LDS via global_load_lds, double
//    buffered, ONE barrier per chunk, prefetch issued right after barrier.
//    Linear LDS dest + source XOR swizzle (o ^= ((row&3)<<4)) applied on the
//    global address; reads use the same XOR -> ~2-way (free) conflicts.
//  - V frags direct from global (L1-shared across the 4 waves).
//  - F frags in registers; S-MFMA in 3 independent chains.
// Grid (64 p-tiles, NS, BB) = 2048 blocks. LDS 45 KB -> 3 blocks/CU.
// ---------------------------------------------------------------------------
__global__ __launch_bounds__(256) void flash_kernel(
    const unsigned short* __restrict__ Fh, const unsigned short* __restrict__ Fl,
    const unsigned short* __restrict__ Kh, const unsigned short* __restrict__ Kl,
    const unsigned short* __restrict__ VT,  // [BB][256][4096]
    const float* __restrict__ mmg,          // [BB][4096]
    float* __restrict__ Up,                 // [NS][BB][4096][256]
    float* __restrict__ Dp)                 // [NS][BB][4096]
{
    __shared__ unsigned short KsS[2][2][32][160];   // [buf][h/l][row][k] 40 KB
    __shared__ unsigned short P_lds[4][16][40];     // per-wave P tile 5 KB

    int t = threadIdx.x;
    int wave = t >> 6, lane = t & 63;
    int l15 = lane & 15, lq = lane >> 4;

    int b  = blockIdx.z;
    int sp = blockIdx.y;
    int pw = blockIdx.x * 64 + wave * 16;
    int lbase = sp * (LP / NS);

    const unsigned short* Fh_b = Fh + (size_t)b * LP * KP;
    const unsigned short* Fl_b = Fl + (size_t)b * LP * KP;
    const unsigned short* Kh_b = Kh + (size_t)b * LP * KP;
    const unsigned short* Kl_b = Kl + (size_t)b * LP * KP;
    const unsigned short* VT_b = VT + (size_t)b * N2 * LP;
    const float* mm_b = mmg + (size_t)b * LP;

    // ---- staging precompute: this wave stages bytes [wave*5120, +5120) of
    // the 20 KB K-region (flat over [hl][row][o]); 5 calls of 1 KB.
    const unsigned short* ksrc[5];
    int krow_s[5];
    int koff_s[5];
#pragma unroll
    for (int i = 0; i < 5; i++) {
        int x = wave * 5120 + i * 1024 + lane * 16;  // flat byte
        int hl = (x >= 10240);
        int o2 = x - hl * 10240;
        int row = o2 / 320;
        int o = o2 - row * 320;
        int osw = o ^ ((row & 3) << 4);              // source swizzle
        ksrc[i] = (hl ? Kl_b : Kh_b) + (osw >> 1);
        krow_s[i] = row;
        koff_s[i] = 0;
        (void)koff_s;
    }
    char* lds0 = (char*)KsS + wave * 5120;

    // ---- F fragments: rows pw..pw+15, k = kc*32 + lq*8
    bf16x8 fh[5], fl[5];
    {
        size_t fbase = (size_t)(pw + l15) * KP + lq * 8;
#pragma unroll
        for (int kc = 0; kc < 5; kc++) {
            fh[kc] = *(const bf16x8*)&Fh_b[fbase + kc * 32];
            fl[kc] = *(const bf16x8*)&Fl_b[fbase + kc * 32];
        }
    }

    f32x4 zero4 = {0.f, 0.f, 0.f, 0.f};
    f32x4 acc[16];
#pragma unroll
    for (int n = 0; n < 16; n++) acc[n] = zero4;
    float d_[4] = {0.f, 0.f, 0.f, 0.f};

    // prologue: stage chunk 0 into buf 0
    {
        size_t lrow = (size_t)lbase * KP;
#pragma unroll
        for (int i = 0; i < 5; i++)
            gl_lds16(ksrc[i] + lrow + (size_t)krow_s[i] * KP, lds0 + i * 1024);
    }

    for (int ch = 0; ch < NCH; ch++) {
        int cur = ch & 1;
        int l0 = lbase + ch * 32;
        __syncthreads();   // drains staging of buf[cur]; fences prev reads

        if (ch + 1 < NCH) {
            size_t lrow = (size_t)(l0 + 32) * KP;
#pragma unroll
            for (int i = 0; i < 5; i++)
                gl_lds16(ksrc[i] + lrow + (size_t)krow_s[i] * KP,
                         lds0 + (cur ^ 1) * 20480 + i * 1024);
        }

        // ---- S phase: two 16-wide l-subtiles from LDS K
        float e_[2][4], mmh[2];
        int swb = (l15 & 3) << 4;
#pragma unroll
        for (int h = 0; h < 2; h++) {
            mmh[h] = mm_b[l0 + h * 16 + l15];
            const char* kbase = (const char*)KsS + cur * 20480 + (h * 16 + l15) * 320;
            f32x4 s0 = zero4, s1 = zero4, s2 = zero4;
#pragma unroll
            for (int kc = 0; kc < 5; kc++) {
                int off = (kc * 64 + lq * 16) ^ swb;
                bf16x8 kvh = *(const bf16x8*)(kbase + off);
                s0 = __builtin_amdgcn_mfma_f32_16x16x32_bf16(fh[kc], kvh, s0, 0, 0, 0);
                s2 = __builtin_amdgcn_mfma_f32_16x16x32_bf16(fl[kc], kvh, s2, 0, 0, 0);
            }
#pragma unroll
            for (int kc = 0; kc < 5; kc++) {
                int off = (kc * 64 + lq * 16) ^ swb;
                bf16x8 kvl = *(const bf16x8*)(kbase + 10240 + off);
                s1 = __builtin_amdgcn_mfma_f32_16x16x32_bf16(fh[kc], kvl, s1, 0, 0, 0);
            }
            f32x4 s = (s0 + s1) + s2;
#pragma unroll
            for (int r = 0; r < 4; r++) {
                float z = (mmh[h] > 0.f) ? 10.f * s[r] : 0.f;
                float e = __expf(z - 60.f);
                d_[r] += e;
                e_[h][r] = e * mmh[h];
            }
        }

        // ---- P tile: D-frag -> [p][l] per-wave LDS, read back as A-frag
#pragma unroll
        for (int h = 0; h < 2; h++)
#pragma unroll
            for (int r = 0; r < 4; r++)
                P_lds[wave][lq * 4 + r][h * 16 + l15] = pack_rne(e_[h][r]);
        bf16x8 pa = *(const bf16x8*)&P_lds[wave][l15][lq * 8];

        // ---- O phase: 16 c-tiles, V direct from global
#pragma unroll
        for (int g = 0; g < 4; g++) {
            bf16x8 vb[4];
            size_t vbase = (size_t)(g * 64 + l15) * LP + l0 + lq * 8;
#pragma unroll
            for (int nn = 0; nn < 4; nn++)
                vb[nn] = *(const bf16x8*)&VT_b[vbase + (size_t)(nn * 16) * LP];
#pragma unroll
            for (int nn = 0; nn < 4; nn++)
                acc[g * 4 + nn] = __builtin_amdgcn_mfma_f32_16x16x32_bf16(pa, vb[nn], acc[g * 4 + nn], 0, 0, 0);
        }
    }

    // ---- epilogue: finish partial denom across the 16 lanes of each row
#pragma unroll
    for (int s = 1; s < 16; s <<= 1)
#pragma unroll
        for (int r = 0; r < 4; r++) d_[r] += __shfl_xor(d_[r], s);

    if (l15 == 0) {
        float* dp = Dp + ((size_t)sp * BB + b) * LP;
#pragma unroll
        for (int r = 0; r < 4; r++) dp[pw + lq * 4 + r] = d_[r];
    }
    float* Uo = Up + ((size_t)sp * BB + b) * LP * N2;
#pragma unroll
    for (int g = 0; g < 4; g++)
#pragma unroll
        for (int nn = 0; nn < 4; nn++) {
            int col = g * 64 + nn * 16 + l15;
#pragma unroll
            for (int r = 0; r < 4; r++)
                Uo[(size_t)(pw + lq * 4 + r) * N2 + col] = acc[g * 4 + nn][r];
        }
}

// ---------------------------------------------------------------------------
// merge: U = (sum_sp Up) / (sum_sp Dp). Streaming, one row per block.
// ---------------------------------------------------------------------------
__global__ __launch_bounds__(256) void merge_kernel(
    const float* __restrict__ Up, const float* __restrict__ Dp,
    float* __restrict__ U)
{
    size_t row = blockIdx.x;            // b*LP + p
    int c = threadIdx.x;
    float d = 0.f, a = 0.f;
#pragma unroll
    for (int s = 0; s < NS; s++) {
        d += Dp[(size_t)s * BB * LP + row];
        a += Up[((size_t)s * BB * LP + row) * N2 + c];
    }
    U[row * N2 + c] = a / d;
}

// ---------------------------------------------------------------------------
// gather / overlap-add (upright), fp32 out
// ---------------------------------------------------------------------------
__global__ __launch_bounds__(256) void gather_kernel(
    const float* __restrict__ U, float* __restrict__ out)
{
    int idx = blockIdx.x * 256 + threadIdx.x;
    int ox = idx & 127;
    int t1 = idx >> 7;
    int oy = t1 & 127;
    int t2 = t1 >> 7;
    int c = t2 & 15;
    int b = t2 >> 4;

    float sum = 0.f;
    int d0y = (oy + 1) & 1, d0x = (ox + 1) & 1;
#pragma unroll
    for (int iy = 0; iy < 2; iy++) {
        int dy = d0y + 2 * iy;
        int y = (oy + 1 - dy) >> 1;
        if (y < 0 || y > 63) continue;
#pragma unroll
        for (int ix = 0; ix < 2; ix++) {
            int dx = d0x + 2 * ix;
            int x = (ox + 1 - dx) >> 1;
            if (x < 0 || x > 63) continue;
            sum += U[((long)b * LP + y * 64 + x) * N2 + c * 16 + dy * 4 + dx];
        }
    }
    out[idx] = sum * 0.25f;
}

// ---------------------------------------------------------------------------
extern "C" void kernel_launch(void* const* d_in, const int* in_sizes, int n_in,
                              void* d_out, int out_size, void* d_ws, size_t ws_size,
                              hipStream_t stream)
{
    const void* fg   = d_in[0];
    const void* bg   = d_in[1];
    const void* mask = d_in[2];
    float* out = (float*)d_out;

    char* w = (char*)d_ws;
    size_t o = 0;
    int*            flag = (int*)(w + o);            o += 16;
    unsigned short* Fh   = (unsigned short*)(w + o); o += (size_t)BB * LP * KP * 2;
    unsigned short* Fl   = (unsigned short*)(w + o); o += (size_t)BB * LP * KP * 2;
    unsigned short* Kh   = (unsigned short*)(w + o); o += (size_t)BB * LP * KP * 2;
    unsigned short* Kl   = (unsigned short*)(w + o); o += (size_t)BB * LP * KP * 2;
    unsigned short* VT   = (unsigned short*)(w + o); o += (size_t)BB * N2 * LP * 2;
    float*          U    = (float*)(w + o);          o += (size_t)BB * LP * N2 * 4;
    float*          mmg  = (float*)(w + o);          o += (size_t)BB * LP * 4;
    float*          Dp   = (float*)(w + o);          o += (size_t)NS * BB * LP * 4;
    float*          Up   = (float*)(w + o);          o += (size_t)NS * BB * LP * N2 * 4;

    detect_kernel<<<1, 64, 0, stream>>>((const unsigned int*)fg, flag);
    prep_kernel<<<BB * LP / 4, 256, 0, stream>>>(fg, bg, mask, flag, Fh, Fl, Kh, Kl, mmg);
    vT_kernel<<<dim3(LP / 16, BB), 256, 0, stream>>>(bg, flag, VT);

    flash_kernel<<<dim3(64, NS, BB), 256, 0, stream>>>(Fh, Fl, Kh, Kl, VT, mmg, Up, Dp);
    merge_kernel<<<BB * LP, 256, 0, stream>>>(Up, Dp, U);

    gather_kernel<<<(BB * CC * HH * WW) / 256, 256, 0, stream>>>(U, out);
}